// Round 9
// baseline (287.237 us; speedup 1.0000x reference)
//
#include <hip/hip_runtime.h>
#include <hip/hip_bf16.h>
#include <hip/hip_cooperative_groups.h>

namespace cg = cooperative_groups;

// Causal attention head. B=4, T=4096, C=384, H=16. fp32 in/out.
// Round 9: SINGLE cooperative kernel (R8 evidence: three structurally
// different flash versions all within noise -> kernels sum to ~20us and
// ~30us was inter-dispatch/graph-node overhead; attack dispatch count).
//   Phase 0: W -> WT bf16 (spread over grid)          } grid.sync()
//   Phase A: qkv MFMA, M-tile=block, 4-wave K-split   } grid.sync()
//   Phase B: flash, R8's S^T register-P core, 4-wave key-split,
//            in-block LDS merge, direct out write (no PO/PL, no merge kernel).
// Co-residency: 1024 blocks x 256 thr = 4 blocks/CU; LDS 9.2KB/block,
// __launch_bounds__(256,4) caps VGPR at 128 -> 4 blocks/CU fits.
// Heavy/light interleave: qt = h ? 255-p : p balances any 8-block window.

constexpr int B_DIM = 4;
constexpr int T_SEQ = 4096;
constexpr int C_DIM = 384;
constexpr int H_DIM = 16;
constexpr int NROW  = B_DIM * T_SEQ; // 16384

typedef __bf16 bf16x8 __attribute__((ext_vector_type(8)));
typedef float  f32x4  __attribute__((ext_vector_type(4)));

__device__ __forceinline__ unsigned short f2bf(float f) {
  unsigned int u = __builtin_bit_cast(unsigned int, f);
  u += 0x7fffu + ((u >> 16) & 1u);   // RNE (finite inputs)
  return (unsigned short)(u >> 16);
}
__device__ __forceinline__ bf16x8 as_bf16x8(uint4 u) {
  return __builtin_bit_cast(bf16x8, u);
}
__device__ __forceinline__ unsigned pk2(float a, float b) {
  float2 t; t.x = a; t.y = b;
  __hip_bfloat162 h = __float22bfloat162_rn(t);  // v_cvt_pk_bf16_f32
  unsigned u;
  __builtin_memcpy(&u, &h, 4);
  return u;
}

__global__ __launch_bounds__(256, 4) void fused_head(
    const float* __restrict__ x,
    const float* __restrict__ Wk, const float* __restrict__ Wq,
    const float* __restrict__ Wv,
    unsigned short* __restrict__ Kb,   // [NROW][16] bf16
    unsigned short* __restrict__ Qb,   // [NROW][32] bf16, scaled, padded
    unsigned short* __restrict__ VTb,  // [B][16][T] bf16
    unsigned short* __restrict__ WT,   // [3][16][384] bf16
    float* __restrict__ out)
{
  __shared__ float smem[2304];         // A: mrg [3][12][64]; B: mrgO+mrgL
  const int tid  = threadIdx.x;
  const int w    = tid >> 6;
  const int lane = tid & 63;
  const int quad = lane >> 4;
  const int col  = lane & 15;
  const int blk  = blockIdx.x;
  cg::grid_group grid = cg::this_grid();

  // ---- Phase 0: W [384][16] fp32 -> WT [m][n=16][k=384] bf16 --------------
  {
    const int i = blk * 256 + tid;     // 18432 < 1024*256
    if (i < 18432) {
      const int m = i / 6144;
      const int r = i - m * 6144;
      const int n = r / 384;
      const int k = r - n * 384;
      const float* __restrict__ W = (m == 0) ? Wk : (m == 1) ? Wq : Wv;
      WT[i] = f2bf(W[k * 16 + n]);
    }
  }
  grid.sync();

  // ---- Phase A: qkv projection, M-tile = blk, 4-wave K-split (3 kk each) --
  {
    const int r0 = blk << 4;
    const int kb = w * 3;
    const float4* __restrict__ xp =
        reinterpret_cast<const float4*>(x + (size_t)(r0 + col) * C_DIM) + quad * 2;
    float4 araw[6];
#pragma unroll
    for (int kk = 0; kk < 3; ++kk) {
      araw[2 * kk]     = xp[(kb + kk) * 8];
      araw[2 * kk + 1] = xp[(kb + kk) * 8 + 1];
    }

    const uint4* __restrict__ bk_ = reinterpret_cast<const uint4*>(
        WT + (size_t)col * 384 + quad * 8);
    const uint4* __restrict__ bq_ = bk_ + 768;    // +6144 shorts
    const uint4* __restrict__ bv_ = bk_ + 1536;   // +12288 shorts

    f32x4 ck = {0.f, 0.f, 0.f, 0.f};
    f32x4 cq = {0.f, 0.f, 0.f, 0.f};
    f32x4 cv = {0.f, 0.f, 0.f, 0.f};
#pragma unroll
    for (int kk = 0; kk < 3; ++kk) {
      uint4 pk;
      const float4 a0 = araw[2 * kk], a1 = araw[2 * kk + 1];
      pk.x = pk2(a0.x, a0.y);
      pk.y = pk2(a0.z, a0.w);
      pk.z = pk2(a1.x, a1.y);
      pk.w = pk2(a1.z, a1.w);
      const bf16x8 av = as_bf16x8(pk);
      ck = __builtin_amdgcn_mfma_f32_16x16x32_bf16(av, as_bf16x8(bk_[(kb + kk) * 4]), ck, 0, 0, 0);
      cq = __builtin_amdgcn_mfma_f32_16x16x32_bf16(av, as_bf16x8(bq_[(kb + kk) * 4]), cq, 0, 0, 0);
      cv = __builtin_amdgcn_mfma_f32_16x16x32_bf16(av, as_bf16x8(bv_[(kb + kk) * 4]), cv, 0, 0, 0);
    }

    if (w != 0) {
      float* m0 = smem + (w - 1) * 768;
#pragma unroll
      for (int r = 0; r < 4; ++r) {
        m0[r * 64 + lane]        = ck[r];
        m0[(4 + r) * 64 + lane]  = cq[r];
        m0[(8 + r) * 64 + lane]  = cv[r];
      }
    }
    __syncthreads();
    if (w == 0) {
      const float SC = 0.25f * 1.44269504088896341f;  // scale * log2(e)
#pragma unroll
      for (int r = 0; r < 4; ++r) {
        float vk = ck[r], vq = cq[r], vv = cv[r];
#pragma unroll
        for (int w2 = 0; w2 < 3; ++w2) {
          vk += smem[w2 * 768 + r * 64 + lane];
          vq += smem[w2 * 768 + (4 + r) * 64 + lane];
          vv += smem[w2 * 768 + (8 + r) * 64 + lane];
        }
        const int row = r0 + quad * 4 + r;
        Kb[row * 16 + col]      = f2bf(vk);
        Qb[row * 32 + col]      = f2bf(vq * SC);
        Qb[row * 32 + 16 + col] = 0;
        const int bb = row >> 12, t = row & 4095;
        VTb[(((size_t)(bb * 16 + col)) << 12) + t] = f2bf(vv);
      }
    }
  }
  grid.sync();

  // ---- Phase B: flash, S^T register-P core (R8-verified), 4-wave split ----
  {
    const int p  = blk >> 3;
    const int h2 = (blk >> 2) & 1;
    const int b  = blk & 3;
    const int qt = h2 ? 255 - p : p;    // heavy/light interleave per 8 blocks
    const int r0 = qt << 4;

    // Q as B-operand: B[k=h=quad*8+j][n=query=col]; h>=16 zero-padded.
    const bf16x8 qb = as_bf16x8(*reinterpret_cast<const uint4*>(
        Qb + (((size_t)(b * T_SEQ + r0 + col)) << 5) + quad * 8));

    f32x4 o = {0.f, 0.f, 0.f, 0.f};   // O^T frag: col=query, row(quad*4+r)=h
    float l = 0.f;

    const unsigned short* Kbase = Kb + ((size_t)(b * T_SEQ) << 4);
    const unsigned short* Vrow  = VTb + (((size_t)(b * 16 + col)) << 12); // h=col
    const int nch = (qt + 4) >> 2;

    for (int c = w; c < nch; c += 4) {
      const int kt0 = c << 2;
      const bool diag = (kt0 + 4 > qt);   // wave-uniform

#pragma unroll
      for (int i = 0; i < 2; ++i) {
        const int vbase = kt0 * 16 + i * 32 + quad * 4;
        const uint2 v0 = *reinterpret_cast<const uint2*>(Vrow + vbase);
        const uint2 v1 = *reinterpret_cast<const uint2*>(Vrow + vbase + 16);

        float pp[2][4];
#pragma unroll
        for (int t2 = 0; t2 < 2; ++t2) {
          const int kt = kt0 + 2 * i + t2;
          // K A-frag: A[m=key=col][k=h=quad*8+j]; quads 2,3 overrun into the
          // next 16-short row -> garbage * Q zero-pad = 0.
          const uint4 kf = *reinterpret_cast<const uint4*>(
              Kbase + (((size_t)(kt * 16 + col)) << 4) + quad * 8);
          f32x4 z = {0.f, 0.f, 0.f, 0.f};
          f32x4 s = __builtin_amdgcn_mfma_f32_16x16x32_bf16(
              as_bf16x8(kf), qb, z, 0, 0, 0);
          if (diag) {
            const int kb0 = kt * 16 + quad * 4 - r0;
#pragma unroll
            for (int r = 0; r < 4; ++r)
              if (kb0 + r > col) s[r] = -1e30f;
          }
#pragma unroll
          for (int r = 0; r < 4; ++r) {
            pp[t2][r] = __builtin_amdgcn_exp2f(s[r]);   // exp2(-1e30) = 0
            l += pp[t2][r];
          }
        }

        uint4 pb;
        pb.x = pk2(pp[0][0], pp[0][1]);
        pb.y = pk2(pp[0][2], pp[0][3]);
        pb.z = pk2(pp[1][0], pp[1][1]);
        pb.w = pk2(pp[1][2], pp[1][3]);
        const uint4 va = make_uint4(v0.x, v0.y, v1.x, v1.y);
        o = __builtin_amdgcn_mfma_f32_16x16x32_bf16(
            as_bf16x8(va), as_bf16x8(pb), o, 0, 0, 0);
      }
    }

    // l: reduce across the 4 quads sharing each query col
    l += __shfl_xor(l, 16);
    l += __shfl_xor(l, 32);

    // in-block merge: mrgO [4][16][16] at smem[0..1023], mrgL [4][16] at 1024
    float* mrgO = smem;
    float* mrgL = smem + 1024;
#pragma unroll
    for (int r = 0; r < 4; ++r)
      mrgO[w * 256 + (quad * 4 + r) * 16 + col] = o[r];
    if (quad == 0) mrgL[w * 16 + col] = l;
    __syncthreads();

    if (w == 0) {
      const float L = mrgL[col] + mrgL[16 + col] + mrgL[32 + col] + mrgL[48 + col];
      const float rinv = 1.0f / L;
      float4 O;
#pragma unroll
      for (int r = 0; r < 4; ++r) {
        float s = 0.f;
#pragma unroll
        for (int w2 = 0; w2 < 4; ++w2)
          s += mrgO[w2 * 256 + (quad * 4 + r) * 16 + col];
        (&O.x)[r] = s * rinv;
      }
      // query=col, h=quad*4+r -> out[(b*T+r0+col)*16 + quad*4], 16B/lane
      *reinterpret_cast<float4*>(
          out + (((size_t)(b * T_SEQ + r0 + col)) << 4) + quad * 4) = O;
    }
  }
}

extern "C" void kernel_launch(void* const* d_in, const int* in_sizes, int n_in,
                              void* d_out, int out_size, void* d_ws, size_t ws_size,
                              hipStream_t stream) {
  const float* x  = (const float*)d_in[0];
  const float* Wk = (const float*)d_in[1];
  const float* Wq = (const float*)d_in[2];
  const float* Wv = (const float*)d_in[3];
  float* outp = (float*)d_out;

  // ws (shorts): Qb [NROW*32] | Kb [NROW*16] | 64 slack | VTb [NROW*16] | WT [18432]
  unsigned short* Qb  = (unsigned short*)d_ws;
  unsigned short* Kb  = Qb + (size_t)NROW * 32;
  unsigned short* VTb = Kb + (size_t)NROW * 16 + 64;
  unsigned short* WT  = VTb + (size_t)NROW * 16;

  void* args[] = {(void*)&x, (void*)&Wk, (void*)&Wq, (void*)&Wv,
                  (void*)&Kb, (void*)&Qb, (void*)&VTb, (void*)&WT,
                  (void*)&outp};
  hipLaunchCooperativeKernel((const void*)fused_head, dim3(1024), dim3(256),
                             args, 0, stream);
}

// Round 10
// 131.622 us; speedup vs baseline: 2.1823x; 2.1823x over previous
//
#include <hip/hip_runtime.h>
#include <hip/hip_bf16.h>

// Causal attention head. B=4, T=4096, C=384, H=16. fp32 in/out.
// Round 10: revert cooperative fusion (R9: grid.sync() cost ~90us each,
// fused kernel 202us @ 3.5% VALUBusy). R9 also measured the harness floor:
// total - kernel = 85us (256MB ws re-poison + restores + replay). So: back
// to stream kernels, but only TWO dispatches:
//  - qkv_fused: per-block W->WT conversion into LDS (72KB from L2; stride
//    392 shorts -> 2-way banks = free), then R9 Phase-A qkv MFMA with
//    B-frags from LDS; LDS reused for the cross-wave merge after a barrier.
//  - flash: R9 Phase-B core (S^T register-P, zero-LDS loop) standalone,
//    in-block 4-wave key-split + LDS merge + direct out write. Heavy-first.

constexpr int B_DIM = 4;
constexpr int T_SEQ = 4096;
constexpr int C_DIM = 384;
constexpr int H_DIM = 16;
constexpr int NROW  = B_DIM * T_SEQ; // 16384

constexpr int WSTR  = 392;           // LDS WT row stride in shorts (pad 384+8)
constexpr int WMAT  = 16 * WSTR;     // 6272 shorts per matrix = 784 uint4

typedef __bf16 bf16x8 __attribute__((ext_vector_type(8)));
typedef float  f32x4  __attribute__((ext_vector_type(4)));

__device__ __forceinline__ unsigned short f2bf(float f) {
  unsigned int u = __builtin_bit_cast(unsigned int, f);
  u += 0x7fffu + ((u >> 16) & 1u);   // RNE (finite inputs)
  return (unsigned short)(u >> 16);
}
__device__ __forceinline__ bf16x8 as_bf16x8(uint4 u) {
  return __builtin_bit_cast(bf16x8, u);
}
__device__ __forceinline__ unsigned pk2(float a, float b) {
  float2 t; t.x = a; t.y = b;
  __hip_bfloat162 h = __float22bfloat162_rn(t);  // v_cvt_pk_bf16_f32
  unsigned u;
  __builtin_memcpy(&u, &h, 4);
  return u;
}

// ---------------------------------------------------------------------------
// Kernel 1: fused W-convert + QKV projection.
// grid 1024 x 256thr. Each block: (a) convert W[384][16]x3 fp32 -> LDS WT
// [m][n=16][k=384] bf16 (row stride 392), (b) 16-row M-tile qkv via MFMA,
// 4-wave K-split (3 x K=32 each), (c) merge in reused LDS, wave-0 epilogue.
// ---------------------------------------------------------------------------
__global__ __launch_bounds__(256) void qkv_fused(
    const float* __restrict__ x,
    const float* __restrict__ Wk, const float* __restrict__ Wq,
    const float* __restrict__ Wv,
    unsigned short* __restrict__ Kb,   // [NROW][16]
    unsigned short* __restrict__ Qb,   // [NROW][32] scaled + zero-padded
    unsigned short* __restrict__ VTb)  // [B][16][T]
{
  __shared__ __attribute__((aligned(16))) unsigned short WTl[3 * WMAT]; // 36.8KB
  const int tid  = threadIdx.x;
  const int w    = tid >> 6;
  const int lane = tid & 63;
  const int quad = lane >> 4;
  const int col  = lane & 15;
  const int r0   = blockIdx.x << 4;
  const int kb   = w * 3;              // this wave's kk base (3 of 12)

  // (a) conversion: thread -> (n = tid>>4, k-run of 24 at (tid&15)*24)
  {
    const int n   = tid >> 4;
    const int kb0 = (tid & 15) * 24;
    const float* __restrict__ Ws[3] = {Wk, Wq, Wv};
#pragma unroll
    for (int m = 0; m < 3; ++m) {
      const float* __restrict__ W = Ws[m];
      unsigned short* dst = WTl + m * WMAT + n * WSTR + kb0;
#pragma unroll 8
      for (int kk = 0; kk < 24; ++kk)
        dst[kk] = f2bf(W[(kb0 + kk) * 16 + n]);
    }
  }

  // (b) A-panel preload (this wave's 3 K-iters = 6 float4/lane)
  const float4* __restrict__ xp =
      reinterpret_cast<const float4*>(x + (size_t)(r0 + col) * C_DIM) + quad * 2;
  float4 araw[6];
#pragma unroll
  for (int kk = 0; kk < 3; ++kk) {
    araw[2 * kk]     = xp[(kb + kk) * 8];
    araw[2 * kk + 1] = xp[(kb + kk) * 8 + 1];
  }

  __syncthreads();   // WTl ready

  // B-frag LDS pointers (uint4 units; WMAT shorts = 784 uint4 - verified)
  const uint4* bk_ = reinterpret_cast<const uint4*>(WTl + col * WSTR + quad * 8);
  const uint4* bq_ = bk_ + 784;
  const uint4* bv_ = bk_ + 1568;

  f32x4 ck = {0.f, 0.f, 0.f, 0.f};
  f32x4 cq = {0.f, 0.f, 0.f, 0.f};
  f32x4 cv = {0.f, 0.f, 0.f, 0.f};
#pragma unroll
  for (int kk = 0; kk < 3; ++kk) {
    uint4 pk;
    const float4 a0 = araw[2 * kk], a1 = araw[2 * kk + 1];
    pk.x = pk2(a0.x, a0.y);
    pk.y = pk2(a0.z, a0.w);
    pk.z = pk2(a1.x, a1.y);
    pk.w = pk2(a1.z, a1.w);
    const bf16x8 av = as_bf16x8(pk);
    ck = __builtin_amdgcn_mfma_f32_16x16x32_bf16(av, as_bf16x8(bk_[(kb + kk) * 4]), ck, 0, 0, 0);
    cq = __builtin_amdgcn_mfma_f32_16x16x32_bf16(av, as_bf16x8(bq_[(kb + kk) * 4]), cq, 0, 0, 0);
    cv = __builtin_amdgcn_mfma_f32_16x16x32_bf16(av, as_bf16x8(bv_[(kb + kk) * 4]), cv, 0, 0, 0);
  }

  // (c) merge: reuse WTl space (all reads of WTl are complete after barrier)
  __syncthreads();
  float* mrg = reinterpret_cast<float*>(WTl);   // [3][12][64] floats used
  if (w != 0) {
    float* m0 = mrg + (w - 1) * 768;
#pragma unroll
    for (int r = 0; r < 4; ++r) {
      m0[r * 64 + lane]       = ck[r];
      m0[(4 + r) * 64 + lane] = cq[r];
      m0[(8 + r) * 64 + lane] = cv[r];
    }
  }
  __syncthreads();
  if (w == 0) {
    const float SC = 0.25f * 1.44269504088896341f;  // softmax scale * log2(e)
#pragma unroll
    for (int r = 0; r < 4; ++r) {
      float vk = ck[r], vq = cq[r], vv = cv[r];
#pragma unroll
      for (int w2 = 0; w2 < 3; ++w2) {
        vk += mrg[w2 * 768 + r * 64 + lane];
        vq += mrg[w2 * 768 + (4 + r) * 64 + lane];
        vv += mrg[w2 * 768 + (8 + r) * 64 + lane];
      }
      const int row = r0 + quad * 4 + r;
      Kb[row * 16 + col]      = f2bf(vk);
      Qb[row * 32 + col]      = f2bf(vq * SC);
      Qb[row * 32 + 16 + col] = 0;
      const int bb = row >> 12, t = row & 4095;
      VTb[(((size_t)(bb * 16 + col)) << 12) + t] = f2bf(vv);
    }
  }
}

// ---------------------------------------------------------------------------
// Kernel 2: flash, S^T register-P core (R8/R9-verified), standalone.
// grid 1024: qt = 255-(blk>>2) heavy-first (LPT), b = blk&3.
// 4 waves split 64-key chunks; in-block LDS merge; direct out write.
// ---------------------------------------------------------------------------
__global__ __launch_bounds__(256) void flash(
    const unsigned short* __restrict__ Qb,
    const unsigned short* __restrict__ Kb,
    const unsigned short* __restrict__ VTb,
    float* __restrict__ out)
{
  __shared__ float mrgO[1024];   // [4][16][16]
  __shared__ float mrgL[64];     // [4][16]
  const int tid  = threadIdx.x;
  const int w    = tid >> 6;
  const int lane = tid & 63;
  const int quad = lane >> 4;
  const int col  = lane & 15;
  const int qt   = 255 - (blockIdx.x >> 2);   // heavy first
  const int b    = blockIdx.x & 3;
  const int r0   = qt << 4;

  // Q as B-operand: B[k=h=quad*8+j][n=query=col]; h>=16 zero-padded.
  const bf16x8 qb = as_bf16x8(*reinterpret_cast<const uint4*>(
      Qb + (((size_t)(b * T_SEQ + r0 + col)) << 5) + quad * 8));

  f32x4 o = {0.f, 0.f, 0.f, 0.f};   // O^T frag: col=query, row(quad*4+r)=h
  float l = 0.f;

  const unsigned short* Kbase = Kb + ((size_t)(b * T_SEQ) << 4);
  const unsigned short* Vrow  = VTb + (((size_t)(b * 16 + col)) << 12); // h=col
  const int nch = (qt + 4) >> 2;

  for (int c = w; c < nch; c += 4) {
    const int kt0 = c << 2;
    const bool diag = (kt0 + 4 > qt);   // wave-uniform

#pragma unroll
    for (int i = 0; i < 2; ++i) {
      const int vbase = kt0 * 16 + i * 32 + quad * 4;
      const uint2 v0 = *reinterpret_cast<const uint2*>(Vrow + vbase);
      const uint2 v1 = *reinterpret_cast<const uint2*>(Vrow + vbase + 16);

      float pp[2][4];
#pragma unroll
      for (int t2 = 0; t2 < 2; ++t2) {
        const int kt = kt0 + 2 * i + t2;
        // K A-frag: A[m=key=col][k=h=quad*8+j]; quads 2,3 overrun into the
        // next 16-short row -> garbage * Q zero-pad = 0.
        const uint4 kf = *reinterpret_cast<const uint4*>(
            Kbase + (((size_t)(kt * 16 + col)) << 4) + quad * 8);
        f32x4 z = {0.f, 0.f, 0.f, 0.f};
        f32x4 s = __builtin_amdgcn_mfma_f32_16x16x32_bf16(
            as_bf16x8(kf), qb, z, 0, 0, 0);
        if (diag) {
          const int kb0 = kt * 16 + quad * 4 - r0;
#pragma unroll
          for (int r = 0; r < 4; ++r)
            if (kb0 + r > col) s[r] = -1e30f;
        }
#pragma unroll
        for (int r = 0; r < 4; ++r) {
          pp[t2][r] = __builtin_amdgcn_exp2f(s[r]);   // exp2(-1e30) = 0
          l += pp[t2][r];
        }
      }

      uint4 pb;
      pb.x = pk2(pp[0][0], pp[0][1]);
      pb.y = pk2(pp[0][2], pp[0][3]);
      pb.z = pk2(pp[1][0], pp[1][1]);
      pb.w = pk2(pp[1][2], pp[1][3]);
      const uint4 va = make_uint4(v0.x, v0.y, v1.x, v1.y);
      o = __builtin_amdgcn_mfma_f32_16x16x32_bf16(
          as_bf16x8(va), as_bf16x8(pb), o, 0, 0, 0);
    }
  }

  // l: reduce across the 4 quads sharing each query col
  l += __shfl_xor(l, 16);
  l += __shfl_xor(l, 32);

#pragma unroll
  for (int r = 0; r < 4; ++r)
    mrgO[w * 256 + (quad * 4 + r) * 16 + col] = o[r];
  if (quad == 0) mrgL[w * 16 + col] = l;
  __syncthreads();

  if (w == 0) {
    const float L = mrgL[col] + mrgL[16 + col] + mrgL[32 + col] + mrgL[48 + col];
    const float rinv = 1.0f / L;
    float4 O;
#pragma unroll
    for (int r = 0; r < 4; ++r) {
      float s = 0.f;
#pragma unroll
      for (int w2 = 0; w2 < 4; ++w2)
        s += mrgO[w2 * 256 + (quad * 4 + r) * 16 + col];
      (&O.x)[r] = s * rinv;
    }
    // query=col, h=quad*4+r -> out[(b*T+r0+col)*16 + quad*4], 16B/lane
    *reinterpret_cast<float4*>(
        out + (((size_t)(b * T_SEQ + r0 + col)) << 4) + quad * 4) = O;
  }
}

extern "C" void kernel_launch(void* const* d_in, const int* in_sizes, int n_in,
                              void* d_out, int out_size, void* d_ws, size_t ws_size,
                              hipStream_t stream) {
  const float* x  = (const float*)d_in[0];
  const float* Wk = (const float*)d_in[1];
  const float* Wq = (const float*)d_in[2];
  const float* Wv = (const float*)d_in[3];
  float* outp = (float*)d_out;

  // ws (shorts): Qb [NROW*32] | Kb [NROW*16] | 64 slack | VTb [NROW*16]
  unsigned short* Qb  = (unsigned short*)d_ws;
  unsigned short* Kb  = Qb + (size_t)NROW * 32;
  unsigned short* VTb = Kb + (size_t)NROW * 16 + 64;

  qkv_fused<<<1024, 256, 0, stream>>>(x, Wk, Wq, Wv, Kb, Qb, VTb);
  flash<<<1024, 256, 0, stream>>>(Qb, Kb, VTb, outp);
}

// Round 11
// 107.009 us; speedup vs baseline: 2.6842x; 1.2300x over previous
//
#include <hip/hip_runtime.h>
#include <hip/hip_bf16.h>

// Causal attention head. B=4, T=4096, C=384, H=16. fp32 in/out.
// Round 11: best-of-each-round recombination.
//   R10 lesson: per-block W conversion repeated 1024x = ~25us regression;
//   keep wconv as its own tiny dispatch (converts once).
//   Config: wconv (R5) + qkv_mfma (R5, 1024x128) + flash (R10: S^T
//   register-P loop, in-block LDS merge, direct out write; no PO/PL).
// Measured context: harness floor ~85us (R9: total-kernel with 1 node);
// structural best ~97us. R6 (4 dispatches + merge + PO/PL) = 104.0.

constexpr int B_DIM = 4;
constexpr int T_SEQ = 4096;
constexpr int C_DIM = 384;
constexpr int H_DIM = 16;
constexpr int NROW  = B_DIM * T_SEQ; // 16384

typedef __bf16 bf16x8 __attribute__((ext_vector_type(8)));
typedef float  f32x4  __attribute__((ext_vector_type(4)));

__device__ __forceinline__ unsigned short f2bf(float f) {
  unsigned int u = __builtin_bit_cast(unsigned int, f);
  u += 0x7fffu + ((u >> 16) & 1u);   // RNE (finite inputs)
  return (unsigned short)(u >> 16);
}
__device__ __forceinline__ bf16x8 as_bf16x8(uint4 u) {
  return __builtin_bit_cast(bf16x8, u);
}
__device__ __forceinline__ unsigned pk2(float a, float b) {
  float2 t; t.x = a; t.y = b;
  __hip_bfloat162 h = __float22bfloat162_rn(t);  // v_cvt_pk_bf16_f32
  unsigned u;
  __builtin_memcpy(&u, &h, 4);
  return u;
}

// ---------------------------------------------------------------------------
// Kernel 0: W -> WT bf16, layout [m][n=16][k=384]. 18432 elements, once.
// ---------------------------------------------------------------------------
__global__ __launch_bounds__(256) void wconv(
    const float* __restrict__ Wk, const float* __restrict__ Wq,
    const float* __restrict__ Wv, unsigned short* __restrict__ WT) {
  const int i = blockIdx.x * 256 + threadIdx.x;   // grid 72*256 = 18432
  const int m = i / 6144;
  const int r = i - m * 6144;
  const int n = r / 384;
  const int k = r - n * 384;
  const float* __restrict__ W = (m == 0) ? Wk : (m == 1) ? Wq : Wv;
  WT[i] = f2bf(W[k * 16 + n]);
}

// ---------------------------------------------------------------------------
// Kernel 1: QKV projection via MFMA, 2-way K-split (R5-proven).
// block = 128 thr (2 waves), grid = 1024 (one 16-row M-tile each).
// A-frag: A[m=col][k=quad*8+j]; B-frag from WT (L2/L1-resident);
// C-frag: row=quad*4+r, col=lane&15. LDS merge, wave-0 epilogue.
// ---------------------------------------------------------------------------
__global__ __launch_bounds__(128) void qkv_mfma(
    const float* __restrict__ x, const unsigned short* __restrict__ WT,
    unsigned short* __restrict__ Kb,   // [NROW][16]
    unsigned short* __restrict__ Qb,   // [NROW][32] scaled + zero-padded
    unsigned short* __restrict__ VTb)  // [B][16][T]
{
  const int tid  = threadIdx.x;
  const int w    = tid >> 6;           // 0..1
  const int lane = tid & 63;
  const int quad = lane >> 4;
  const int col  = lane & 15;
  const int r0   = blockIdx.x << 4;
  const int kb   = w * 6;              // this wave's kk base

  __shared__ float mrg[12][64];

  const float4* __restrict__ xp =
      reinterpret_cast<const float4*>(x + (size_t)(r0 + col) * C_DIM) + quad * 2;
  float4 araw[12];
#pragma unroll
  for (int kk = 0; kk < 6; ++kk) {
    araw[2 * kk]     = xp[(kb + kk) * 8];
    araw[2 * kk + 1] = xp[(kb + kk) * 8 + 1];
  }

  const uint4* __restrict__ bk = reinterpret_cast<const uint4*>(
      WT + (size_t)col * 384 + quad * 8);
  const uint4* __restrict__ bq = bk + 768;    // +6144 shorts
  const uint4* __restrict__ bv = bk + 1536;   // +12288 shorts

  f32x4 ck = {0.f, 0.f, 0.f, 0.f};
  f32x4 cq = {0.f, 0.f, 0.f, 0.f};
  f32x4 cv = {0.f, 0.f, 0.f, 0.f};
#pragma unroll
  for (int kk = 0; kk < 6; ++kk) {
    uint4 pk;
    const float4 a0 = araw[2 * kk], a1 = araw[2 * kk + 1];
    pk.x = pk2(a0.x, a0.y);
    pk.y = pk2(a0.z, a0.w);
    pk.z = pk2(a1.x, a1.y);
    pk.w = pk2(a1.z, a1.w);
    const bf16x8 av = as_bf16x8(pk);
    ck = __builtin_amdgcn_mfma_f32_16x16x32_bf16(av, as_bf16x8(bk[(kb + kk) * 4]), ck, 0, 0, 0);
    cq = __builtin_amdgcn_mfma_f32_16x16x32_bf16(av, as_bf16x8(bq[(kb + kk) * 4]), cq, 0, 0, 0);
    cv = __builtin_amdgcn_mfma_f32_16x16x32_bf16(av, as_bf16x8(bv[(kb + kk) * 4]), cv, 0, 0, 0);
  }

  if (w == 1) {
#pragma unroll
    for (int r = 0; r < 4; ++r) {
      mrg[r][lane]     = ck[r];
      mrg[4 + r][lane] = cq[r];
      mrg[8 + r][lane] = cv[r];
    }
  }
  __syncthreads();
  if (w == 0) {
    const float SC = 0.25f * 1.44269504088896341f;  // softmax scale * log2(e)
#pragma unroll
    for (int r = 0; r < 4; ++r) {
      const float vk = ck[r] + mrg[r][lane];
      const float vq = cq[r] + mrg[4 + r][lane];
      const float vv = cv[r] + mrg[8 + r][lane];
      const int row = r0 + quad * 4 + r;
      Kb[row * 16 + col]      = f2bf(vk);
      Qb[row * 32 + col]      = f2bf(vq * SC);
      Qb[row * 32 + 16 + col] = 0;
      const int bb = row >> 12, t = row & 4095;
      VTb[(((size_t)(bb * 16 + col)) << 12) + t] = f2bf(vv);
    }
  }
}

// ---------------------------------------------------------------------------
// Kernel 2: flash, S^T register-P core (R8/R9/R10-verified).
// grid 1024: qt = 255-(blk>>2) heavy-first (LPT), b = blk&3.
// 4 waves split 64-key chunks; in-block LDS merge; direct out write.
// ---------------------------------------------------------------------------
__global__ __launch_bounds__(256) void flash(
    const unsigned short* __restrict__ Qb,
    const unsigned short* __restrict__ Kb,
    const unsigned short* __restrict__ VTb,
    float* __restrict__ out)
{
  __shared__ float mrgO[1024];   // [4][16][16]
  __shared__ float mrgL[64];     // [4][16]
  const int tid  = threadIdx.x;
  const int w    = tid >> 6;
  const int lane = tid & 63;
  const int quad = lane >> 4;
  const int col  = lane & 15;
  const int qt   = 255 - (blockIdx.x >> 2);   // heavy first
  const int b    = blockIdx.x & 3;
  const int r0   = qt << 4;

  // Q as B-operand: B[k=h=quad*8+j][n=query=col]; h>=16 zero-padded.
  const bf16x8 qb = as_bf16x8(*reinterpret_cast<const uint4*>(
      Qb + (((size_t)(b * T_SEQ + r0 + col)) << 5) + quad * 8));

  f32x4 o = {0.f, 0.f, 0.f, 0.f};   // O^T frag: col=query, row(quad*4+r)=h
  float l = 0.f;

  const unsigned short* Kbase = Kb + ((size_t)(b * T_SEQ) << 4);
  const unsigned short* Vrow  = VTb + (((size_t)(b * 16 + col)) << 12); // h=col
  const int nch = (qt + 4) >> 2;

  for (int c = w; c < nch; c += 4) {
    const int kt0 = c << 2;
    const bool diag = (kt0 + 4 > qt);   // wave-uniform

#pragma unroll
    for (int i = 0; i < 2; ++i) {
      const int vbase = kt0 * 16 + i * 32 + quad * 4;
      const uint2 v0 = *reinterpret_cast<const uint2*>(Vrow + vbase);
      const uint2 v1 = *reinterpret_cast<const uint2*>(Vrow + vbase + 16);

      float pp[2][4];
#pragma unroll
      for (int t2 = 0; t2 < 2; ++t2) {
        const int kt = kt0 + 2 * i + t2;
        // K A-frag: A[m=key=col][k=h=quad*8+j]; quads 2,3 overrun into the
        // next 16-short row -> garbage * Q zero-pad = 0.
        const uint4 kf = *reinterpret_cast<const uint4*>(
            Kbase + (((size_t)(kt * 16 + col)) << 4) + quad * 8);
        f32x4 z = {0.f, 0.f, 0.f, 0.f};
        f32x4 s = __builtin_amdgcn_mfma_f32_16x16x32_bf16(
            as_bf16x8(kf), qb, z, 0, 0, 0);
        if (diag) {
          const int kb0 = kt * 16 + quad * 4 - r0;
#pragma unroll
          for (int r = 0; r < 4; ++r)
            if (kb0 + r > col) s[r] = -1e30f;
        }
#pragma unroll
        for (int r = 0; r < 4; ++r) {
          pp[t2][r] = __builtin_amdgcn_exp2f(s[r]);   // exp2(-1e30) = 0
          l += pp[t2][r];
        }
      }

      uint4 pb;
      pb.x = pk2(pp[0][0], pp[0][1]);
      pb.y = pk2(pp[0][2], pp[0][3]);
      pb.z = pk2(pp[1][0], pp[1][1]);
      pb.w = pk2(pp[1][2], pp[1][3]);
      const uint4 va = make_uint4(v0.x, v0.y, v1.x, v1.y);
      o = __builtin_amdgcn_mfma_f32_16x16x32_bf16(
          as_bf16x8(va), as_bf16x8(pb), o, 0, 0, 0);
    }
  }

  // l: reduce across the 4 quads sharing each query col
  l += __shfl_xor(l, 16);
  l += __shfl_xor(l, 32);

#pragma unroll
  for (int r = 0; r < 4; ++r)
    mrgO[w * 256 + (quad * 4 + r) * 16 + col] = o[r];
  if (quad == 0) mrgL[w * 16 + col] = l;
  __syncthreads();

  if (w == 0) {
    const float L = mrgL[col] + mrgL[16 + col] + mrgL[32 + col] + mrgL[48 + col];
    const float rinv = 1.0f / L;
    float4 O;
#pragma unroll
    for (int r = 0; r < 4; ++r) {
      float s = 0.f;
#pragma unroll
      for (int w2 = 0; w2 < 4; ++w2)
        s += mrgO[w2 * 256 + (quad * 4 + r) * 16 + col];
      (&O.x)[r] = s * rinv;
    }
    // query=col, h=quad*4+r -> out[(b*T+r0+col)*16 + quad*4], 16B/lane
    *reinterpret_cast<float4*>(
        out + (((size_t)(b * T_SEQ + r0 + col)) << 4) + quad * 4) = O;
  }
}

extern "C" void kernel_launch(void* const* d_in, const int* in_sizes, int n_in,
                              void* d_out, int out_size, void* d_ws, size_t ws_size,
                              hipStream_t stream) {
  const float* x  = (const float*)d_in[0];
  const float* Wk = (const float*)d_in[1];
  const float* Wq = (const float*)d_in[2];
  const float* Wv = (const float*)d_in[3];
  float* outp = (float*)d_out;

  // ws (shorts): Qb [NROW*32] | Kb [NROW*16] | 64 slack | VTb [NROW*16] | WT [18432]
  unsigned short* Qb  = (unsigned short*)d_ws;
  unsigned short* Kb  = Qb + (size_t)NROW * 32;
  unsigned short* VTb = Kb + (size_t)NROW * 16 + 64;
  unsigned short* WT  = VTb + (size_t)NROW * 16;

  wconv<<<72, 256, 0, stream>>>(Wk, Wq, Wv, WT);
  qkv_mfma<<<1024, 128, 0, stream>>>(x, WT, Kb, Qb, VTb);
  flash<<<1024, 256, 0, stream>>>(Qb, Kb, VTb, outp);
}